// Round 5
// baseline (197.047 us; speedup 1.0000x reference)
//
#include <hip/hip_runtime.h>

#define NN 100
#define EE 262144
#define NB 128
#define NTH 256
#define SP_CNT 8

// ws layout (float offsets):
//   bar  @ 0      : 16 ints  (grid barrier counters; zeroed by memset)
//   MS   @ 16     : 512      (BN sum[256], sumsq[256]; zeroed by memset)
//   S    @ 528    : 80000    (8 partial adjacency copies; zeroed by memset)
//   A    @ 80528  : 10000
//   dinv @ 90528  : 100
//   h1   @ 90628  : 6400
//   h2   @ 97028  : 12800
//   h3   @ 109828 : 25600
//   y    @ 135428 : 1000
#define WS_MS  16
#define WS_S   528
#define WS_A   80528
#define WS_DI  90528
#define WS_H1  90628
#define WS_H2  97028
#define WS_H3  109828
#define WS_Y   135428
#define MEMSET_BYTES ((16 + 512 + 80000) * 4)

// Device-scope grid barrier. All NB blocks resident (128 blocks, 256 thr,
// 52 KB LDS << capacity of 256 CUs). __threadfence() on gfx950 emits the
// agent-scope L2 writeback/invalidate needed for cross-XCD visibility.
__device__ __forceinline__ void gridbar(int* bar, int k) {
    __threadfence();                      // release: every thread drains stores
    __syncthreads();
    if (threadIdx.x == 0) {
        atomicAdd(&bar[k], 1);            // device-scope
        for (int it = 0; it < (1 << 22); ++it) {   // capped spin (hang guard)
            if (__hip_atomic_load(&bar[k], __ATOMIC_RELAXED,
                                  __HIP_MEMORY_SCOPE_AGENT) >= NB) break;
            __builtin_amdgcn_s_sleep(2);
        }
        __threadfence();                  // acquire: invalidate L1 + XCD L2
    }
    __syncthreads();
}

__global__ __launch_bounds__(NTH) void mega_kernel(
    const float* __restrict__ x,  const int* __restrict__ ei,
    const float* __restrict__ ew,
    const float* __restrict__ W1, const float* __restrict__ b1,
    const float* __restrict__ W2, const float* __restrict__ b2,
    const float* __restrict__ W3, const float* __restrict__ b3,
    const float* __restrict__ gamma, const float* __restrict__ beta,
    const float* __restrict__ lw1, const float* __restrict__ lb1,
    const float* __restrict__ lw2, const float* __restrict__ lb2,
    float* __restrict__ ws, float* __restrict__ out)
{
    __shared__ float lds[13056];          // 52 KB, reused per phase
    int*   bar   = (int*)ws;
    float* MS    = ws + WS_MS;
    float* S     = ws + WS_S;
    float* Ag    = ws + WS_A;
    float* dinvg = ws + WS_DI;
    float* h1g   = ws + WS_H1;
    float* h2g   = ws + WS_H2;
    float* h3g   = ws + WS_H3;
    float* yg    = ws + WS_Y;
    const int tid = threadIdx.x;
    const int blk = blockIdx.x;

    // ---- P0: edge scatter, all 32768 threads, 2 quads each ----
    {
        int t = blk * NTH + tid;
#pragma unroll
        for (int q = t; q < EE / 4; q += NB * NTH) {
            int4   s4 = ((const int4*)ei)[q];
            int4   d4 = ((const int4*)(ei + EE))[q];
            float4 w4 = ((const float4*)ew)[q];
            float* Sp = S + (q & (SP_CNT - 1)) * (NN * NN);
            atomicAdd(&Sp[d4.x * NN + s4.x], w4.x);
            atomicAdd(&Sp[d4.y * NN + s4.y], w4.y);
            atomicAdd(&Sp[d4.z * NN + s4.z], w4.z);
            atomicAdd(&Sp[d4.w * NN + s4.w], w4.w);
        }
    }
    gridbar(bar, 0);

    // ---- P1: degrees -> dinv (100 blocks, one row each) ----
    if (blk < NN) {
        float* red = lds;
        if (tid < NN) {
            float s = 0.f;
#pragma unroll
            for (int p = 0; p < SP_CNT; ++p)
                s += S[p * NN * NN + blk * NN + tid];
            red[tid] = s;
        }
        __syncthreads();
        if (tid == 0) {
            float deg = 1.f;                       // self-loop weight
            for (int i = 0; i < NN; ++i) deg += red[i];
            dinvg[blk] = rsqrtf(deg);
        }
    }
    gridbar(bar, 1);

    // ---- P2: A row + layer 1 (100 blocks) ----
    if (blk < NN) {
        float* xl   = lds;            // 2700
        float* dv   = lds + 2700;     // 100
        float* Arow = lds + 2800;     // 100
        float* g1   = lds + 2900;     // 27
        for (int i = tid; i < NN * 27; i += NTH) xl[i] = x[i];
        if (tid < NN) dv[tid] = dinvg[tid];
        __syncthreads();
        if (tid < NN) {
            float s = 0.f;
#pragma unroll
            for (int p = 0; p < SP_CNT; ++p)
                s += S[p * NN * NN + blk * NN + tid];
            float v = dv[blk] * dv[tid] * s;
            if (tid == blk) v += dv[blk] * dv[blk];
            Arow[tid] = v;
            Ag[blk * NN + tid] = v;
        }
        __syncthreads();
        if (tid < 27) {                          // g1 = A_row @ x
            float acc = 0.f;
#pragma unroll 4
            for (int m = 0; m < NN; ++m) acc += Arow[m] * xl[m * 27 + tid];
            g1[tid] = acc;
        }
        __syncthreads();
        if (tid < 64) {                          // h1 = relu(g1 @ W1 + b1)
            float acc = b1[tid];
#pragma unroll
            for (int c = 0; c < 27; ++c) acc += g1[c] * W1[c * 64 + tid];
            h1g[blk * 64 + tid] = fmaxf(acc, 0.f);
        }
    }
    gridbar(bar, 2);

    // ---- P3: layer 2 (100 blocks) ----
    if (blk < NN) {
        float* h1l = lds;             // 6400
        float* Ar  = lds + 6400;      // 100
        float* g2  = lds + 6500;      // 64
        for (int i = tid; i < NN * 16; i += NTH)
            ((float4*)h1l)[i] = ((const float4*)h1g)[i];
        if (tid < NN) Ar[tid] = Ag[blk * NN + tid];
        __syncthreads();
        if (tid < 64) {
            float acc = 0.f;
#pragma unroll 4
            for (int m = 0; m < NN; ++m) acc += Ar[m] * h1l[m * 64 + tid];
            g2[tid] = acc;
        }
        __syncthreads();
        if (tid < 128) {
            float acc = b2[tid];
#pragma unroll 8
            for (int c = 0; c < 64; ++c) acc += g2[c] * W2[c * 128 + tid];
            h2g[blk * 128 + tid] = fmaxf(acc, 0.f);
        }
    }
    gridbar(bar, 3);

    // ---- P4: layer 3 + BN stats (100 blocks) ----
    if (blk < NN) {
        float* h2l = lds;             // 12800
        float* Ar  = lds + 12800;     // 100
        float* g3  = lds + 12900;     // 128
        for (int i = tid; i < NN * 32; i += NTH)
            ((float4*)h2l)[i] = ((const float4*)h2g)[i];
        if (tid < NN) Ar[tid] = Ag[blk * NN + tid];
        __syncthreads();
        if (tid < 128) {
            float acc = 0.f;
#pragma unroll 4
            for (int m = 0; m < NN; ++m) acc += Ar[m] * h2l[m * 128 + tid];
            g3[tid] = acc;
        }
        __syncthreads();
        {
            int j = tid;                          // 256 outputs, 1/thread
            float acc = b3[j];
#pragma unroll 8
            for (int c = 0; c < 128; ++c) acc += g3[c] * W3[c * 256 + j];
            float v = fmaxf(acc, 0.f);
            h3g[blk * 256 + j] = v;
            atomicAdd(&MS[j], v);
            atomicAdd(&MS[256 + j], v * v);
        }
    }
    gridbar(bar, 4);

    // ---- P5: BN apply + lin1 (100 blocks) ----
    if (blk < NN) {
        float* v = lds;               // 256
        {
            int c = tid;
            float s1 = MS[c], s2 = MS[256 + c];
            float mu  = s1 * 0.01f;
            float var = s2 * 0.01f - mu * mu;
            float sc  = gamma[c] * rsqrtf(var + 1e-5f);
            v[c] = h3g[blk * 256 + c] * sc + (beta[c] - mu * sc);
        }
        __syncthreads();
        const int wave = tid >> 6, lane = tid & 63;
        for (int k = wave; k < 10; k += 4) {
            float4 hv = *(const float4*)(v + lane * 4);
            float4 w  = *(const float4*)(lw1 + k * 256 + lane * 4);
            float acc = hv.x * w.x + hv.y * w.y + hv.z * w.z + hv.w * w.w;
#pragma unroll
            for (int off = 32; off; off >>= 1) acc += __shfl_down(acc, off);
            if (lane == 0) yg[blk * 10 + k] = fmaxf(acc + lb1[k], 0.f);
        }
    }
    gridbar(bar, 5);

    // ---- P6: lin2 (128 blocks, one output each) ----
    {
        float* part = lds;            // 4
        const float4* y4 = (const float4*)yg;
        const float4* w4 = (const float4*)(lw2 + blk * 1000);
        float acc = 0.f;
        if (tid < 250) {
            float4 a = y4[tid], b = w4[tid];
            acc = a.x * b.x + a.y * b.y + a.z * b.z + a.w * b.w;
        }
#pragma unroll
        for (int off = 32; off; off >>= 1) acc += __shfl_down(acc, off);
        if ((tid & 63) == 0) part[tid >> 6] = acc;
        __syncthreads();
        if (tid == 0)
            out[blk] = part[0] + part[1] + part[2] + part[3] + lb2[blk];
    }
}

extern "C" void kernel_launch(void* const* d_in, const int* in_sizes, int n_in,
                              void* d_out, int out_size, void* d_ws, size_t ws_size,
                              hipStream_t stream) {
    const float* x     = (const float*)d_in[0];
    const int*   ei    = (const int*)d_in[1];
    const float* ew    = (const float*)d_in[2];
    const float* W1    = (const float*)d_in[3];
    const float* b1    = (const float*)d_in[4];
    const float* W2    = (const float*)d_in[5];
    const float* b2    = (const float*)d_in[6];
    const float* W3    = (const float*)d_in[7];
    const float* b3    = (const float*)d_in[8];
    const float* gamma = (const float*)d_in[9];
    const float* beta  = (const float*)d_in[10];
    const float* lw1   = (const float*)d_in[11];
    const float* lb1   = (const float*)d_in[12];
    const float* lw2   = (const float*)d_in[13];
    const float* lb2   = (const float*)d_in[14];

    float* ws  = (float*)d_ws;
    float* out = (float*)d_out;

    hipMemsetAsync(ws, 0, MEMSET_BYTES, stream);     // bar + MS + S
    mega_kernel<<<NB, NTH, 0, stream>>>(x, ei, ew, W1, b1, W2, b2, W3, b3,
                                        gamma, beta, lw1, lb1, lw2, lb2,
                                        ws, out);
}

// Round 6
// 130.353 us; speedup vs baseline: 1.5116x; 1.5116x over previous
//
#include <hip/hip_runtime.h>

#define NN 100
#define EE 262144
#define NP 64          // scatter partial copies (one per scatter block)

// ws layout (float offsets):
//   P    @ 0      : NP*10000 = 640000  (scatter partials; fully overwritten)
//   Ssum @ 640000 : 10000
//   MS   @ 650000 : 512   (BN sum/sumsq; zeroed by rowsum block 0)
//   dinv @ 650512 : 100
//   A    @ 650624 : 10000
//   h1   @ 660624 : 6400
//   h2   @ 667024 : 12800
//   h3   @ 679824 : 25600
//   y    @ 705424 : 1000
#define WS_SSUM 640000
#define WS_MS   650000
#define WS_DI   650512
#define WS_A    650624
#define WS_H1   660624
#define WS_H2   667024
#define WS_H3   679824
#define WS_Y    705424

// ---- scatter: per-block LDS histogram, NO global atomics ----
__global__ __launch_bounds__(512) void scatter_kernel(
    const int* __restrict__ ei, const float* __restrict__ ew,
    float* __restrict__ P)
{
    __shared__ float hist[NN * NN];          // 40 KB
    const int tid = threadIdx.x, blk = blockIdx.x;
    for (int i = tid; i < 2500; i += 512)
        ((float4*)hist)[i] = make_float4(0.f, 0.f, 0.f, 0.f);
    __syncthreads();
    const int base = blk * 1024;             // 1024 quads = 4096 edges per block
#pragma unroll
    for (int q = base + tid; q < base + 1024; q += 512) {
        int4   s4 = ((const int4*)ei)[q];
        int4   d4 = ((const int4*)(ei + EE))[q];
        float4 w4 = ((const float4*)ew)[q];
        atomicAdd(&hist[d4.x * NN + s4.x], w4.x);    // ds_add_f32 (LDS)
        atomicAdd(&hist[d4.y * NN + s4.y], w4.y);
        atomicAdd(&hist[d4.z * NN + s4.z], w4.z);
        atomicAdd(&hist[d4.w * NN + s4.w], w4.w);
    }
    __syncthreads();
    float4* out = (float4*)(P + blk * 10000);
    for (int i = tid; i < 2500; i += 512) out[i] = ((const float4*)hist)[i];
}

// ---- rowsum: reduce NP partials per row -> Ssum, deg -> dinv; zero MS ----
__global__ __launch_bounds__(256) void rowsum_kernel(
    const float* __restrict__ P, float* __restrict__ Ssum,
    float* __restrict__ dinvg, float* __restrict__ MS)
{
    __shared__ float row[NN];
    __shared__ float part[25];
    const int tid = threadIdx.x, d = blockIdx.x;
    if (d == 0 && tid < 128)
        ((float4*)MS)[tid] = make_float4(0.f, 0.f, 0.f, 0.f);
    if (tid < NN) row[tid] = 0.f;
    __syncthreads();
    if (tid < 250) {                         // (p-group, col4): coalesced 25-f4 rows
        int c4 = tid % 25, p0 = tid / 25;
        float4 acc = make_float4(0.f, 0.f, 0.f, 0.f);
        for (int p = p0; p < NP; p += 10) {
            float4 v = ((const float4*)P)[p * 2500 + d * 25 + c4];
            acc.x += v.x; acc.y += v.y; acc.z += v.z; acc.w += v.w;
        }
        atomicAdd(&row[c4 * 4 + 0], acc.x);
        atomicAdd(&row[c4 * 4 + 1], acc.y);
        atomicAdd(&row[c4 * 4 + 2], acc.z);
        atomicAdd(&row[c4 * 4 + 3], acc.w);
    }
    __syncthreads();
    if (tid < NN) Ssum[d * NN + tid] = row[tid];
    if (tid < 25) {
        float4 v = ((const float4*)row)[tid];
        part[tid] = v.x + v.y + v.z + v.w;
    }
    __syncthreads();
    if (tid == 0) {
        float deg = 1.f;                     // self-loop weight 1
#pragma unroll
        for (int i = 0; i < 25; ++i) deg += part[i];
        dinvg[d] = rsqrtf(deg);
    }
}

// ---- A row + layer 1 (100 blocks) ----
__global__ __launch_bounds__(256) void a_l1_kernel(
    const float* __restrict__ Ssum, const float* __restrict__ dinvg,
    const float* __restrict__ x, const float* __restrict__ W1,
    const float* __restrict__ b1, float* __restrict__ Ag,
    float* __restrict__ h1g)
{
    __shared__ float xl[NN * 27];
    __shared__ float dv[NN];
    __shared__ float Arow[NN];
    __shared__ float g1[27];
    const int tid = threadIdx.x, d = blockIdx.x;
    for (int i = tid; i < NN * 27; i += 256) xl[i] = x[i];
    if (tid < NN) dv[tid] = dinvg[tid];
    __syncthreads();
    if (tid < NN) {
        float v = dv[d] * dv[tid] * Ssum[d * NN + tid];
        if (tid == d) v += dv[d] * dv[d];
        Arow[tid] = v;
        Ag[d * NN + tid] = v;
    }
    __syncthreads();
    if (tid < 27) {                          // g1 = A_row @ x
        float acc = 0.f;
#pragma unroll 4
        for (int m = 0; m < NN; ++m) acc += Arow[m] * xl[m * 27 + tid];
        g1[tid] = acc;
    }
    __syncthreads();
    if (tid < 64) {                          // h1 = relu(g1 @ W1 + b1)
        float acc = b1[tid];
#pragma unroll
        for (int c = 0; c < 27; ++c) acc += g1[c] * W1[c * 64 + tid];
        h1g[d * 64 + tid] = fmaxf(acc, 0.f);
    }
}

// ---- layer 2 (100 blocks) ----
__global__ __launch_bounds__(256) void l2_kernel(
    const float* __restrict__ A, const float* __restrict__ h1,
    const float* __restrict__ W2, const float* __restrict__ b2,
    float* __restrict__ h2)
{
    __shared__ float h1l[NN * 64];
    __shared__ float Ar[NN];
    __shared__ float g2[64];
    const int tid = threadIdx.x, n = blockIdx.x;
    for (int i = tid; i < NN * 16; i += 256)
        ((float4*)h1l)[i] = ((const float4*)h1)[i];
    if (tid < NN) Ar[tid] = A[n * NN + tid];
    __syncthreads();
    if (tid < 64) {
        float acc = 0.f;
#pragma unroll 4
        for (int m = 0; m < NN; ++m) acc += Ar[m] * h1l[m * 64 + tid];
        g2[tid] = acc;
    }
    __syncthreads();
    if (tid < 128) {
        float acc = b2[tid];
#pragma unroll 8
        for (int c = 0; c < 64; ++c) acc += g2[c] * W2[c * 128 + tid];
        h2[n * 128 + tid] = fmaxf(acc, 0.f);
    }
}

// ---- layer 3 + BN stats (100 blocks) ----
__global__ __launch_bounds__(256) void l3_kernel(
    const float* __restrict__ A, const float* __restrict__ h2,
    const float* __restrict__ W3, const float* __restrict__ b3,
    float* __restrict__ h3, float* __restrict__ MS)
{
    __shared__ float h2l[NN * 128];
    __shared__ float Ar[NN];
    __shared__ float g3[128];
    const int tid = threadIdx.x, n = blockIdx.x;
    for (int i = tid; i < NN * 32; i += 256)
        ((float4*)h2l)[i] = ((const float4*)h2)[i];
    if (tid < NN) Ar[tid] = A[n * NN + tid];
    __syncthreads();
    if (tid < 128) {
        float acc = 0.f;
#pragma unroll 4
        for (int m = 0; m < NN; ++m) acc += Ar[m] * h2l[m * 128 + tid];
        g3[tid] = acc;
    }
    __syncthreads();
    {
        int j = tid;                         // 256 outputs, 1/thread
        float acc = b3[j];
#pragma unroll 8
        for (int c = 0; c < 128; ++c) acc += g3[c] * W3[c * 256 + j];
        float v = fmaxf(acc, 0.f);
        h3[n * 256 + j] = v;
        atomicAdd(&MS[j], v);
        atomicAdd(&MS[256 + j], v * v);
    }
}

// ---- lin1 (+BN apply): 100 blocks x 1 wave ----
__global__ __launch_bounds__(64) void lin1_kernel(
    const float* __restrict__ h3, const float* __restrict__ ms,
    const float* __restrict__ gamma, const float* __restrict__ beta,
    const float* __restrict__ lw1, const float* __restrict__ lb1,
    float* __restrict__ y)
{
    __shared__ float v[256];
    const int lane = threadIdx.x, n = blockIdx.x;
    {
        int c0 = lane * 4;
        float4 h  = *(const float4*)(h3 + n * 256 + c0);
        float4 s1 = *(const float4*)(ms + c0);
        float4 s2 = *(const float4*)(ms + 256 + c0);
        float4 gm = *(const float4*)(gamma + c0);
        float4 bt = *(const float4*)(beta + c0);
        float4 r;
#define BNAP(f) { \
        float mu = s1.f * 0.01f; \
        float var = s2.f * 0.01f - mu * mu; \
        float sc = gm.f * rsqrtf(var + 1e-5f); \
        r.f = h.f * sc + (bt.f - mu * sc); }
        BNAP(x) BNAP(y) BNAP(z) BNAP(w)
#undef BNAP
        *(float4*)(v + c0) = r;
    }
    __syncthreads();
    const int c0 = lane * 4;
    float4 hv = *(const float4*)(v + c0);
#pragma unroll
    for (int k = 0; k < 10; ++k) {
        float4 w = *(const float4*)(lw1 + k * 256 + c0);
        float acc = hv.x * w.x + hv.y * w.y + hv.z * w.z + hv.w * w.w;
#pragma unroll
        for (int off = 32; off; off >>= 1) acc += __shfl_down(acc, off);
        if (lane == 0) y[n * 10 + k] = fmaxf(acc + lb1[k], 0.f);
    }
}

// ---- lin2: 128 blocks x 1 wave ----
__global__ __launch_bounds__(64) void lin2_kernel(
    const float* __restrict__ y, const float* __restrict__ lw2,
    const float* __restrict__ lb2, float* __restrict__ out)
{
    const int lane = threadIdx.x, j = blockIdx.x;
    const float4* y4 = (const float4*)y;
    const float4* w4 = (const float4*)(lw2 + j * 1000);
    float acc = 0.f;
#pragma unroll
    for (int i = lane; i < 250; i += 64) {
        float4 a = y4[i], b = w4[i];
        acc += a.x * b.x + a.y * b.y + a.z * b.z + a.w * b.w;
    }
#pragma unroll
    for (int off = 32; off; off >>= 1) acc += __shfl_down(acc, off);
    if (lane == 0) out[j] = acc + lb2[j];
}

extern "C" void kernel_launch(void* const* d_in, const int* in_sizes, int n_in,
                              void* d_out, int out_size, void* d_ws, size_t ws_size,
                              hipStream_t stream) {
    const float* x     = (const float*)d_in[0];
    const int*   ei    = (const int*)d_in[1];
    const float* ew    = (const float*)d_in[2];
    const float* W1    = (const float*)d_in[3];
    const float* b1    = (const float*)d_in[4];
    const float* W2    = (const float*)d_in[5];
    const float* b2    = (const float*)d_in[6];
    const float* W3    = (const float*)d_in[7];
    const float* b3    = (const float*)d_in[8];
    const float* gamma = (const float*)d_in[9];
    const float* beta  = (const float*)d_in[10];
    const float* lw1   = (const float*)d_in[11];
    const float* lb1   = (const float*)d_in[12];
    const float* lw2   = (const float*)d_in[13];
    const float* lb2   = (const float*)d_in[14];

    float* ws   = (float*)d_ws;
    float* P    = ws;
    float* Ssum = ws + WS_SSUM;
    float* MS   = ws + WS_MS;
    float* dinv = ws + WS_DI;
    float* A    = ws + WS_A;
    float* h1   = ws + WS_H1;
    float* h2   = ws + WS_H2;
    float* h3   = ws + WS_H3;
    float* y    = ws + WS_Y;
    float* out  = (float*)d_out;

    scatter_kernel<<<NP, 512, 0, stream>>>(ei, ew, P);
    rowsum_kernel<<<NN, 256, 0, stream>>>(P, Ssum, dinv, MS);
    a_l1_kernel<<<NN, 256, 0, stream>>>(Ssum, dinv, x, W1, b1, A, h1);
    l2_kernel<<<NN, 256, 0, stream>>>(A, h1, W2, b2, h2);
    l3_kernel<<<NN, 256, 0, stream>>>(A, h2, W3, b3, h3, MS);
    lin1_kernel<<<NN, 64, 0, stream>>>(h3, MS, gamma, beta, lw1, lb1, y);
    lin2_kernel<<<128, 64, 0, stream>>>(y, lw2, lb2, out);
}